// Round 1
// 470.908 us; speedup vs baseline: 1.1255x; 1.1255x over previous
//
#include <hip/hip_runtime.h>
#include <hip/hip_bf16.h>

// ---- problem constants ----
#define B_    8
#define T_    4096
#define H_    16
#define NB_   32
#define D_    1024
#define NS_   512      // H*NB
#define PF_   1024     // 2*NS
#define HID_  128
#define RTOK  32768    // B*T

#define LCH   128      // scan chunk length (was 256: 128 blocks -> half the CUs idle)
#define WARM  64       // gate^64 = sigmoid(-1.7)^64 ~ 1e-52: warm-start exact
#define NCH   32       // T/LCH

typedef __attribute__((ext_vector_type(8))) short short8;
typedef __attribute__((ext_vector_type(4))) float floatx4;
typedef unsigned short us;

__device__ __forceinline__ float bf2f(us u){
    union { unsigned int i; float f; } v; v.i = ((unsigned int)u) << 16; return v.f;
}
__device__ __forceinline__ us f2bf(float f){
    union { float f; unsigned int i; } v; v.f = f;
    unsigned int r = v.i + 0x7fffu + ((v.i >> 16) & 1u);
    return (us)(r >> 16);
}
__device__ __forceinline__ float gelu_exact(float x){
    return 0.5f * x * (1.0f + erff(x * 0.70710678118654752f));
}
__device__ __forceinline__ floatx4 mfma16(short8 a, short8 b, floatx4 c){
    return __builtin_amdgcn_mfma_f32_16x16x32_bf16(a, b, c, 0, 0, 0);
}
__device__ __forceinline__ short8 ldfrag(const us* p){
    return *(const short8*)p;   // 16B aligned -> ds_read_b128
}
__device__ __forceinline__ float ldany(const void* p, int i, int df){
    return df ? bf2f(((const us*)p)[i]) : ((const float*)p)[i];
}

// ---------------- input dtype classifier (bf16 vs fp32) ----------------
__global__ void dtype_classify(const us* t, int* dflag){
    __shared__ int good;
    if (threadIdx.x == 0) good = 0;
    __syncthreads();
    int g = 0;
    for (int j = 0; j < 64; ++j){
        us u = t[threadIdx.x * 64 + j];
        int e = (u >> 7) & 0xff;
        if (u == 0 || (e >= 90 && e <= 140)) g++;
    }
    atomicAdd(&good, g);
    __syncthreads();
    if (threadIdx.x == 0) dflag[0] = (good > (16384 * 9) / 10) ? 1 : 0; // 1=bf16
}

// ---------------- mask dtype classifier + decode ----------------
__global__ void mask_classify(const unsigned char* mp, int* flag){
    __shared__ int s_mis, s_oth, s_off1;
    if (threadIdx.x == 0){ s_mis = 0; s_oth = 0; s_off1 = 0; }
    __syncthreads();
    int mis = 0, oth = 0, off1 = 0;
    int base = threadIdx.x * 128;
    for (int i = base; i < base + 128; ++i){
        unsigned char v = mp[i];
        if (v){
            if (i & 3) mis++;
            if ((i & 3) == 1) off1++;
            if (v != 1) oth++;
        }
    }
    atomicAdd(&s_mis, mis); atomicAdd(&s_oth, oth); atomicAdd(&s_off1, off1);
    __syncthreads();
    if (threadIdx.x == 0){
        int f;
        if (s_mis == 0)       f = 0;   // int32 words
        else if (s_oth == 0)  f = 1;   // bool bytes
        else if (s_off1 > 0)  f = 2;   // bf16
        else                  f = 3;   // fp32
        *flag = f;
    }
}

__global__ void mask_decode(const void* mp, const int* flag, float* maskf){
    int i = blockIdx.x * 256 + threadIdx.x;
    if (i >= RTOK) return;
    int f = *flag;
    bool nz;
    if (f == 1)      nz = ((const unsigned char*) mp)[i] != 0;
    else if (f == 2) nz = ((const us*)           mp)[i] != 0;
    else             nz = ((const unsigned int*) mp)[i] != 0;
    maskf[i] = nz ? 1.0f : 0.0f;
}

// ------ weights: transpose + canonicalize to bf16; biases+lg -> cb ------
// cb layout: fb1@0(128) fb2@128(1024) eb1@1152(128) eb2@1280(512) lg@1792(512)
__global__ void prep_weights(const void* fw1, const void* fw2, const void* ew1,
                             const void* ew2, const void* fb1, const void* fb2,
                             const void* eb1, const void* eb2, const void* lg,
                             const int* dflag,
                             us* fw1t, us* fw2t, us* ew1t, us* ew2t, us* cb){
    int df = *dflag;
    for (int idx = blockIdx.x * 256 + threadIdx.x; idx < 461056;
         idx += gridDim.x * 256){
        if (idx < 131072){          // fw1 (1024,128) -> fw1t (128,1024)
            int k = idx >> 7, n = idx & 127;
            fw1t[n * 1024 + k] = f2bf(ldany(fw1, idx, df));
        } else if (idx < 262144){   // fw2 (128,1024) -> fw2t (1024,128)
            int l = idx - 131072, k = l >> 10, n = l & 1023;
            fw2t[n * 128 + k] = f2bf(ldany(fw2, l, df));
        } else if (idx < 393216){   // ew1 (1024,128) -> ew1t (128,1024)
            int l = idx - 262144, k = l >> 7, n = l & 127;
            ew1t[n * 1024 + k] = f2bf(ldany(ew1, l, df));
        } else if (idx < 458752){   // ew2 (128,512) -> ew2t (512,128)
            int l = idx - 393216, k = l >> 9, n = l & 511;
            ew2t[n * 128 + k] = f2bf(ldany(ew2, l, df));
        } else {                    // biases + log_gain
            int l = idx - 458752;
            float v;
            if (l < 128)       v = ldany(fb1, l, df);
            else if (l < 1152) v = ldany(fb2, l - 128, df);
            else if (l < 1280) v = ldany(eb1, l - 1152, df);
            else if (l < 1792) v = ldany(eb2, l - 1280, df);
            else               v = ldany(lg,  l - 1792, df);
            cb[l] = f2bf(v);
        }
    }
}

// stage W^T panel [NR][NC] (row stride GK) into LDS stride NC+8
template<int NR, int NC, int GK, int NT>
__device__ __forceinline__ void stage_wt(us* lds, const us* g,
                                         int row0, int k0, int tid){
    const int LS = NC + 8;
    constexpr int TOT = NR * NC / 8;
    #pragma unroll
    for (int i = tid; i < TOT; i += NT){
        int r  = i / (NC / 8);
        int c8 = (i % (NC / 8)) * 8;
        uint4 v = *(const uint4*)(g + (size_t)(row0 + r) * GK + k0 + c8);
        *(uint4*)(lds + r * LS + c8) = v;
    }
}

// ---------------- fused MLP chain (64 tokens / block, 8 waves) ----------------
// 64 rows amortizes each staged weight panel 2x vs the old 32-row block, and
// 128-wide chunks halve the barrier count (~58/block vs ~112). 8 waves x
// 2 blocks/CU = 16 waves/CU to cover barrier + L2-staging latency.
// delta (fp32) is staged into the theta_hat region of d_out (exact element
// match); the scan later overwrites it in place.
__global__ __launch_bounds__(512, 4) void fused_mlp(
    const void* __restrict__ theta, const void* __restrict__ content,
    const int* __restrict__ dflag, const float* __restrict__ maskf,
    const us* __restrict__ cb,
    const us* __restrict__ fw1t, const us* __restrict__ fw2t,
    const us* __restrict__ ew1t, const us* __restrict__ ew2t,
    float* __restrict__ err_out, float* __restrict__ delta_out)
{
    __shared__ __align__(16) us sPF[64 * 136];   // pos_feat / content / err chunk
    __shared__ __align__(16) us sW [128 * 136];  // weight panel (128 x 128)
    __shared__ __align__(16) us sH [64 * 136];   // hidden (h1 then h2)
    __shared__ float sMask[64];
    // LDS total ~69.9 KB -> 2 blocks/CU

    const int tid  = threadIdx.x;
    const int wid  = tid >> 6;           // 0..7
    const int lane = tid & 63;
    const int q    = lane >> 4;
    const int ln   = lane & 15;
    const int wr   = (wid >> 2) * 32;    // wave row base: 0 / 32
    const int wc   = (wid & 3) * 32;     // wave col base: 0 / 32 / 64 / 96
    const int row0 = blockIdx.x * 64;
    const int df   = *dflag;

    if (tid < 64) sMask[tid] = maskf[row0 + tid];

    // ========== GEMM1: pos_feat @ fw1 ==========
    // pos_feat is PER-HEAD [cos32|sin32]; chunk kc covers heads 2kc,2kc+1
    // (k range kc*128 .. kc*128+128).
    floatx4 h1a[2][2] = {};
    for (int kc = 0; kc < 8; ++kc){
        { // theta chunk (HBM) -> cos/sin panel sPF[64][136]
            int r = tid >> 3, e0 = (tid & 7) * 8;
            size_t off = (size_t)(row0 + r) * NS_ + kc * 64 + e0;
            float xv[8];
            if (df){
                uint4 raw = *(const uint4*)((const us*)theta + off);
                const us* pu = (const us*)&raw;
                #pragma unroll
                for (int j = 0; j < 8; ++j) xv[j] = bf2f(pu[j]);
            } else {
                const float* tp = (const float*)theta + off;
                float4 v0 = *(const float4*)tp;
                float4 v1 = *(const float4*)(tp + 4);
                xv[0]=v0.x; xv[1]=v0.y; xv[2]=v0.z; xv[3]=v0.w;
                xv[4]=v1.x; xv[5]=v1.y; xv[6]=v1.z; xv[7]=v1.w;
            }
            short8 c8v, s8v;
            #pragma unroll
            for (int j = 0; j < 8; ++j){
                float s, c;
                __sincosf(xv[j], &s, &c);
                c8v[j] = (short)f2bf(c);
                s8v[j] = (short)f2bf(s);
            }
            int base = r * 136 + (e0 >> 5) * 64 + (e0 & 31);
            *(short8*)(&sPF[base])      = c8v;
            *(short8*)(&sPF[base + 32]) = s8v;
        }
        stage_wt<128, 128, 1024, 512>(sW, fw1t, 0, kc * 128, tid);
        __syncthreads();
        #pragma unroll
        for (int ks = 0; ks < 4; ++ks){
            short8 a0 = ldfrag(&sPF[(wr + ln)      * 136 + ks * 32 + q * 8]);
            short8 a1 = ldfrag(&sPF[(wr + 16 + ln) * 136 + ks * 32 + q * 8]);
            short8 b0 = ldfrag(&sW [(wc + ln)      * 136 + ks * 32 + q * 8]);
            short8 b1 = ldfrag(&sW [(wc + 16 + ln) * 136 + ks * 32 + q * 8]);
            h1a[0][0] = mfma16(a0, b0, h1a[0][0]);
            h1a[0][1] = mfma16(a0, b1, h1a[0][1]);
            h1a[1][0] = mfma16(a1, b0, h1a[1][0]);
            h1a[1][1] = mfma16(a1, b1, h1a[1][1]);
        }
        __syncthreads();
    }
    // epilogue: +fb1, GELU -> sH
    #pragma unroll
    for (int mt = 0; mt < 2; ++mt)
        #pragma unroll
        for (int nt = 0; nt < 2; ++nt){
            int n = wc + nt * 16 + ln;
            float bias = bf2f(cb[n]);                       // fb1
            #pragma unroll
            for (int r2 = 0; r2 < 4; ++r2){
                int m = wr + mt * 16 + q * 4 + r2;
                sH[m * 136 + n] = f2bf(gelu_exact(h1a[mt][nt][r2] + bias));
            }
        }
    __syncthreads();

    // ===== GEMM2 (h1@fw2) + err + GEMM3 (err@ew1), 128-col chunks =====
    floatx4 h2a[2][2] = {};
    for (int nc = 0; nc < 8; ++nc){
        { // content chunk (HBM, issue first) -> sPF[64][136]
            int r = tid >> 3, c0 = (tid & 7) * 16;
            size_t off = (size_t)(row0 + r) * D_ + nc * 128 + c0;
            if (df){
                const us* cp = (const us*)content + off;
                *(uint4*)(&sPF[r * 136 + c0])     = *(const uint4*)cp;
                *(uint4*)(&sPF[r * 136 + c0 + 8]) = *(const uint4*)(cp + 8);
            } else {
                const float* cp = (const float*)content + off;
                #pragma unroll
                for (int v = 0; v < 2; ++v){
                    float4 a = *(const float4*)(cp + v * 8);
                    float4 b = *(const float4*)(cp + v * 8 + 4);
                    short8 t8;
                    t8[0] = (short)f2bf(a.x); t8[1] = (short)f2bf(a.y);
                    t8[2] = (short)f2bf(a.z); t8[3] = (short)f2bf(a.w);
                    t8[4] = (short)f2bf(b.x); t8[5] = (short)f2bf(b.y);
                    t8[6] = (short)f2bf(b.z); t8[7] = (short)f2bf(b.w);
                    *(short8*)(&sPF[r * 136 + c0 + v * 8]) = t8;
                }
            }
        }
        stage_wt<128, 128, 128, 512>(sW, fw2t, nc * 128, 0, tid);
        __syncthreads();
        floatx4 oa[2][2] = {};
        #pragma unroll
        for (int ks = 0; ks < 4; ++ks){
            short8 a0 = ldfrag(&sH[(wr + ln)      * 136 + ks * 32 + q * 8]);
            short8 a1 = ldfrag(&sH[(wr + 16 + ln) * 136 + ks * 32 + q * 8]);
            short8 b0 = ldfrag(&sW[(wc + ln)      * 136 + ks * 32 + q * 8]);
            short8 b1 = ldfrag(&sW[(wc + 16 + ln) * 136 + ks * 32 + q * 8]);
            oa[0][0] = mfma16(a0, b0, oa[0][0]);
            oa[0][1] = mfma16(a0, b1, oa[0][1]);
            oa[1][0] = mfma16(a1, b0, oa[1][0]);
            oa[1][1] = mfma16(a1, b1, oa[1][1]);
        }
        { // err epilogue: store err_raw (fp32), put masked err back into sPF.
          // Each (m,n) cell is read+written by exactly one owning thread.
            #pragma unroll
            for (int mt = 0; mt < 2; ++mt)
                #pragma unroll
                for (int nt = 0; nt < 2; ++nt){
                    int n = wc + nt * 16 + ln;
                    float bias = bf2f(cb[128 + nc * 128 + n]);   // fb2
                    #pragma unroll
                    for (int r2 = 0; r2 < 4; ++r2){
                        int m = wr + mt * 16 + q * 4 + r2;
                        float obs  = oa[mt][nt][r2] + bias;
                        float eraw = bf2f(sPF[m * 136 + n]) - obs;
                        err_out[(size_t)(row0 + m) * D_ + nc * 128 + n] = eraw;
                        sPF[m * 136 + n] = f2bf(eraw * sMask[m]);
                    }
                }
        }
        __syncthreads();
        stage_wt<128, 128, 1024, 512>(sW, ew1t, 0, nc * 128, tid);
        __syncthreads();
        #pragma unroll
        for (int ks = 0; ks < 4; ++ks){
            short8 a0 = ldfrag(&sPF[(wr + ln)      * 136 + ks * 32 + q * 8]);
            short8 a1 = ldfrag(&sPF[(wr + 16 + ln) * 136 + ks * 32 + q * 8]);
            short8 b0 = ldfrag(&sW [(wc + ln)      * 136 + ks * 32 + q * 8]);
            short8 b1 = ldfrag(&sW [(wc + 16 + ln) * 136 + ks * 32 + q * 8]);
            h2a[0][0] = mfma16(a0, b0, h2a[0][0]);
            h2a[0][1] = mfma16(a0, b1, h2a[0][1]);
            h2a[1][0] = mfma16(a1, b0, h2a[1][0]);
            h2a[1][1] = mfma16(a1, b1, h2a[1][1]);
        }
        __syncthreads();
    }
    // epilogue: +eb1, GELU -> sH
    #pragma unroll
    for (int mt = 0; mt < 2; ++mt)
        #pragma unroll
        for (int nt = 0; nt < 2; ++nt){
            int n = wc + nt * 16 + ln;
            float bias = bf2f(cb[1152 + n]);                // eb1
            #pragma unroll
            for (int r2 = 0; r2 < 4; ++r2){
                int m = wr + mt * 16 + q * 4 + r2;
                sH[m * 136 + n] = f2bf(gelu_exact(h2a[mt][nt][r2] + bias));
            }
        }
    __syncthreads();

    // ========== GEMM4: h2 @ ew2 -> delta (fp32, into theta_hat region) ======
    for (int nc = 0; nc < 4; ++nc){
        stage_wt<128, 128, 128, 512>(sW, ew2t, nc * 128, 0, tid);
        __syncthreads();
        floatx4 da[2][2] = {};
        #pragma unroll
        for (int ks = 0; ks < 4; ++ks){
            short8 a0 = ldfrag(&sH[(wr + ln)      * 136 + ks * 32 + q * 8]);
            short8 a1 = ldfrag(&sH[(wr + 16 + ln) * 136 + ks * 32 + q * 8]);
            short8 b0 = ldfrag(&sW[(wc + ln)      * 136 + ks * 32 + q * 8]);
            short8 b1 = ldfrag(&sW[(wc + 16 + ln) * 136 + ks * 32 + q * 8]);
            da[0][0] = mfma16(a0, b0, da[0][0]);
            da[0][1] = mfma16(a0, b1, da[0][1]);
            da[1][0] = mfma16(a1, b0, da[1][0]);
            da[1][1] = mfma16(a1, b1, da[1][1]);
        }
        #pragma unroll
        for (int mt = 0; mt < 2; ++mt)
            #pragma unroll
            for (int nt = 0; nt < 2; ++nt){
                int n = wc + nt * 16 + ln;
                int col = nc * 128 + n;
                float bias = bf2f(cb[1280 + col]);          // eb2
                #pragma unroll
                for (int r2 = 0; r2 < 4; ++r2){
                    int m = wr + mt * 16 + q * 4 + r2;
                    delta_out[(size_t)(row0 + m) * NS_ + col] = da[mt][nt][r2] + bias;
                }
            }
        __syncthreads();
    }
}

// -------- phase 1: per-chunk warm-start states (separate dispatch, so the
// in-place scan has no cross-block read/write race on delta) --------
__global__ __launch_bounds__(512) void warmup_k(
    const float* __restrict__ delta, const us* __restrict__ cb,
    float* __restrict__ warm)
{
    int c  = threadIdx.x;
    int bi = blockIdx.x;            // b*NCH + ch
    int ch = bi & (NCH - 1);
    float g = 1.0f / (1.0f + expf(-bf2f(cb[1792 + c])));
    float w = 0.0f;
    if (ch > 0){
        int b  = bi >> 5;
        int t0 = ch * LCH;
        const float* dp = delta + ((size_t)b * T_ + t0 - WARM) * NS_ + c;
        #pragma unroll 8
        for (int t = 0; t < WARM; ++t){ w = g * w + *dp; dp += NS_; }
    }
    warm[bi * NS_ + c] = w;
}

// -------- phase 2: in-place scan: out0 holds delta, becomes theta_hat --------
__global__ __launch_bounds__(512) void scan_k(
    const void* __restrict__ theta, const us* __restrict__ cb,
    const int* __restrict__ dflag, const float* __restrict__ warm,
    float* __restrict__ out0, float* __restrict__ gate_out)
{
    int c  = threadIdx.x;           // chain 0..511
    int bi = blockIdx.x;
    int b  = bi >> 5;
    int ch = bi & (NCH - 1);
    float g = 1.0f / (1.0f + expf(-bf2f(cb[1792 + c])));
    if (bi == 0) gate_out[c] = g;

    float d = warm[bi * NS_ + c];
    size_t base = ((size_t)b * T_ + ch * LCH) * NS_ + c;
    float* op = out0 + base;
    if (*dflag){
        const us* tp = (const us*)theta + base;
        #pragma unroll 4
        for (int t = 0; t < LCH; ++t){
            d = g * d + *op;                  // read delta (fp32)
            *op = bf2f(*tp) + d;              // overwrite with theta_hat
            tp += NS_; op += NS_;
        }
    } else {
        const float* tp = (const float*)theta + base;
        #pragma unroll 4
        for (int t = 0; t < LCH; ++t){
            d = g * d + *op;
            *op = *tp + d;
            tp += NS_; op += NS_;
        }
    }
}

extern "C" void kernel_launch(void* const* d_in, const int* in_sizes, int n_in,
                              void* d_out, int out_size, void* d_ws, size_t ws_size,
                              hipStream_t stream)
{
    const void* theta   = d_in[0];
    const void* content = d_in[1];
    const void* maskraw = d_in[2];
    const void* fw1 = d_in[3];  const void* fb1 = d_in[4];
    const void* fw2 = d_in[5];  const void* fb2 = d_in[6];
    const void* ew1 = d_in[7];  const void* eb1 = d_in[8];
    const void* ew2 = d_in[9];  const void* eb2 = d_in[10];
    const void* lg  = d_in[11];

    char* ws = (char*)d_ws;                 // total ws usage: ~1.45 MB
    float* maskf = (float*)ws;              // [0, 131072) -- dead after fused_mlp
    float* warmb = (float*)ws;              // [0, 524288) -- reuses maskf region
    int*   flag  = (int*)(ws + 524288);
    int*   dflag = (int*)(ws + 524292);
    us*    fw1t  = (us*)(ws + 525312);      // 262144 B
    us*    fw2t  = (us*)(ws + 787456);      // 262144 B
    us*    ew1t  = (us*)(ws + 1049600);     // 262144 B
    us*    ew2t  = (us*)(ws + 1311744);     // 131072 B
    us*    cb    = (us*)(ws + 1442816);     // 4608 B

    float* out0 = (float*)d_out;           // theta_hat (16,777,216 fp32) [delta staged here]
    float* out1 = out0 + 16777216;         // err_raw   (33,554,432 fp32)
    float* out2 = out1 + 33554432;         // gate      (512 fp32)

    dtype_classify<<<1, 256, 0, stream>>>((const us*)theta, dflag);
    mask_classify<<<1, 256, 0, stream>>>((const unsigned char*)maskraw, flag);
    mask_decode<<<128, 256, 0, stream>>>(maskraw, flag, maskf);
    prep_weights<<<512, 256, 0, stream>>>(fw1, fw2, ew1, ew2, fb1, fb2, eb1, eb2,
                                          lg, dflag, fw1t, fw2t, ew1t, ew2t, cb);
    fused_mlp<<<RTOK / 64, 512, 0, stream>>>(theta, content, dflag, maskf, cb,
                                             fw1t, fw2t, ew1t, ew2t, out1, out0);
    warmup_k<<<B_ * NCH, 512, 0, stream>>>(out0, cb, warmb);
    scan_k<<<B_ * NCH, 512, 0, stream>>>(theta, cb, dflag, warmb, out0, out2);
}

// Round 2
// 452.412 us; speedup vs baseline: 1.1715x; 1.0409x over previous
//
#include <hip/hip_runtime.h>
#include <hip/hip_bf16.h>

// ---- problem constants ----
#define B_    8
#define T_    4096
#define H_    16
#define NB_   32
#define D_    1024
#define NS_   512      // H*NB
#define PF_   1024     // 2*NS
#define HID_  128
#define RTOK  32768    // B*T

#define LCH   64       // scan chunk length (512 blocks -> 2/CU, 16 waves/CU)
#define WARM  64       // gate^64 = sigmoid(-1.7)^64 ~ 1e-52: warm-start exact
#define NCH   64       // T/LCH

typedef __attribute__((ext_vector_type(8))) short short8;
typedef __attribute__((ext_vector_type(4))) float floatx4;
typedef unsigned short us;

__device__ __forceinline__ float bf2f(us u){
    union { unsigned int i; float f; } v; v.i = ((unsigned int)u) << 16; return v.f;
}
__device__ __forceinline__ us f2bf(float f){
    union { float f; unsigned int i; } v; v.f = f;
    unsigned int r = v.i + 0x7fffu + ((v.i >> 16) & 1u);
    return (us)(r >> 16);
}
__device__ __forceinline__ float gelu_exact(float x){
    return 0.5f * x * (1.0f + erff(x * 0.70710678118654752f));
}
__device__ __forceinline__ floatx4 mfma16(short8 a, short8 b, floatx4 c){
    return __builtin_amdgcn_mfma_f32_16x16x32_bf16(a, b, c, 0, 0, 0);
}
__device__ __forceinline__ short8 ldfrag(const us* p){
    return *(const short8*)p;   // 16B aligned -> ds_read_b128
}
__device__ __forceinline__ float ldany(const void* p, size_t i, int df){
    return df ? bf2f(((const us*)p)[i]) : ((const float*)p)[i];
}
// lgkm-only workgroup barrier: does NOT drain vmcnt, so global prefetches
// (weight frags / theta / content) stay in flight across it.
__device__ __forceinline__ void bar(){
    __builtin_amdgcn_sched_barrier(0);
    asm volatile("s_waitcnt lgkmcnt(0)" ::: "memory");
    __builtin_amdgcn_s_barrier();
    __builtin_amdgcn_sched_barrier(0);
}

// ---------------- input dtype classifier (bf16 vs fp32) ----------------
__global__ void dtype_classify(const us* t, int* dflag){
    __shared__ int good;
    if (threadIdx.x == 0) good = 0;
    __syncthreads();
    int g = 0;
    for (int j = 0; j < 64; ++j){
        us u = t[threadIdx.x * 64 + j];
        int e = (u >> 7) & 0xff;
        if (u == 0 || (e >= 90 && e <= 140)) g++;
    }
    atomicAdd(&good, g);
    __syncthreads();
    if (threadIdx.x == 0) dflag[0] = (good > (16384 * 9) / 10) ? 1 : 0; // 1=bf16
}

// ---------------- mask dtype classifier ----------------
__global__ void mask_classify(const unsigned char* mp, int* flag){
    __shared__ int s_mis, s_oth, s_off1;
    if (threadIdx.x == 0){ s_mis = 0; s_oth = 0; s_off1 = 0; }
    __syncthreads();
    int mis = 0, oth = 0, off1 = 0;
    int base = threadIdx.x * 128;
    for (int i = base; i < base + 128; ++i){
        unsigned char v = mp[i];
        if (v){
            if (i & 3) mis++;
            if ((i & 3) == 1) off1++;
            if (v != 1) oth++;
        }
    }
    atomicAdd(&s_mis, mis); atomicAdd(&s_oth, oth); atomicAdd(&s_off1, off1);
    __syncthreads();
    if (threadIdx.x == 0){
        int f;
        if (s_mis == 0)       f = 0;   // int32 words
        else if (s_oth == 0)  f = 1;   // bool bytes
        else if (s_off1 > 0)  f = 2;   // bf16
        else                  f = 3;   // fp32
        *flag = f;
    }
}

// ------ weights -> bf16 in MFMA-fragment-major order; biases+lg -> cb ------
// Fragment layout (per GEMM): idx = (((chunk*8 + wblk)*4 + ks)*64 + lane)*8 + j
//   where lane = q*16+ln supplies W^T[outcol = wblk*16+ln][k = ks*32 + q*8 + j].
// Scheme A (chunked over K=1024, 128 outs): fw1, ew1.  chunk = k>>7.
// Scheme B (chunked over OUT, K=128): fw2 (1024 outs), ew2 (512 outs). chunk = n>>7.
// cb layout: fb1@0(128) fb2@128(1024) eb1@1152(128) eb2@1280(512) lg@1792(512)
__global__ void prep_weights(const void* fw1, const void* fw2, const void* ew1,
                             const void* ew2, const void* fb1, const void* fb2,
                             const void* eb1, const void* eb2, const void* lg,
                             const int* dflag,
                             us* fw1t, us* fw2t, us* ew1t, us* ew2t, us* cb){
    int df = *dflag;
    for (int idx = blockIdx.x * 256 + threadIdx.x; idx < 461056;
         idx += gridDim.x * 256){
        if (idx < 131072){          // fw1 (1024 k, 128 n) scheme A
            int k = idx >> 7, n = idx & 127;
            int c = k >> 7, kk = k & 127;
            int ks = kk >> 5, qq = (kk >> 3) & 3, j = k & 7;
            int w = n >> 4, ln = n & 15;
            fw1t[(((c*8 + w)*4 + ks)*64 + qq*16 + ln)*8 + j] = f2bf(ldany(fw1, idx, df));
        } else if (idx < 262144){   // fw2 (128 k, 1024 n) scheme B
            int l = idx - 131072; int k = l >> 10, n = l & 1023;
            int c = n >> 7, w = (n >> 4) & 7, ln = n & 15;
            int ks = k >> 5, qq = (k >> 3) & 3, j = k & 7;
            fw2t[(((c*8 + w)*4 + ks)*64 + qq*16 + ln)*8 + j] = f2bf(ldany(fw2, l, df));
        } else if (idx < 393216){   // ew1 (1024 k, 128 n) scheme A
            int l = idx - 262144; int k = l >> 7, n = l & 127;
            int c = k >> 7, kk = k & 127;
            int ks = kk >> 5, qq = (kk >> 3) & 3, j = k & 7;
            int w = n >> 4, ln = n & 15;
            ew1t[(((c*8 + w)*4 + ks)*64 + qq*16 + ln)*8 + j] = f2bf(ldany(ew1, l, df));
        } else if (idx < 458752){   // ew2 (128 k, 512 n) scheme B
            int l = idx - 393216; int k = l >> 9, n = l & 511;
            int c = n >> 7, w = (n >> 4) & 7, ln = n & 15;
            int ks = k >> 5, qq = (k >> 3) & 3, j = k & 7;
            ew2t[(((c*8 + w)*4 + ks)*64 + qq*16 + ln)*8 + j] = f2bf(ldany(ew2, l, df));
        } else {                    // biases + log_gain
            int l = idx - 458752;
            float v;
            if (l < 128)       v = ldany(fb1, l, df);
            else if (l < 1152) v = ldany(fb2, l - 128, df);
            else if (l < 1280) v = ldany(eb1, l - 1152, df);
            else if (l < 1792) v = ldany(eb2, l - 1280, df);
            else               v = ldany(lg,  l - 1792, df);
            cb[l] = f2bf(v);
        }
    }
}

__device__ __forceinline__ void load8(float* xv, const void* p, size_t off, int df){
    if (df){
        uint4 raw = *(const uint4*)((const us*)p + off);
        const us* pu = (const us*)&raw;
        #pragma unroll
        for (int j = 0; j < 8; ++j) xv[j] = bf2f(pu[j]);
    } else {
        const float* tp = (const float*)p + off;
        float4 v0 = *(const float4*)tp;
        float4 v1 = *(const float4*)(tp + 4);
        xv[0]=v0.x; xv[1]=v0.y; xv[2]=v0.z; xv[3]=v0.w;
        xv[4]=v1.x; xv[5]=v1.y; xv[6]=v1.z; xv[7]=v1.w;
    }
}

// ---------------- fused MLP chain (64 tokens / block, 8 waves) ----------------
// Weights: direct L2->VGPR fragment loads (no LDS, no staging barriers).
// LDS: double-buffered sPF (pos_feat, then err) + sH (hidden). 18 lgkm-only
// barriers per block vs 58 vmcnt(0)-draining ones previously.
// Wave tiling: wave w owns output cols w*16..w*16+15, all 64 rows (4 m-frags).
// delta (fp32) goes into the theta_hat region of d_out; scan overwrites in place.
__global__ __launch_bounds__(512, 4) void fused_mlp(
    const void* __restrict__ theta, const void* __restrict__ content,
    const int* __restrict__ dflag,
    const void* __restrict__ maskraw, const int* __restrict__ mflag,
    const us* __restrict__ cb,
    const us* __restrict__ fw1t, const us* __restrict__ fw2t,
    const us* __restrict__ ew1t, const us* __restrict__ ew2t,
    float* __restrict__ err_out, float* __restrict__ delta_out)
{
    __shared__ __align__(16) us sPF[2][64 * 136];  // pos_feat / err (double buf)
    __shared__ __align__(16) us sH[64 * 136];      // hidden (h1 then h2)
    __shared__ float sMask[64];
    // LDS ~51.3 KB

    const int tid  = threadIdx.x;
    const int wid  = tid >> 6;           // 0..7  (out col-block)
    const int lane = tid & 63;
    const int q    = lane >> 4;
    const int ln   = lane & 15;
    const int row0 = blockIdx.x * 64;
    const int df   = *dflag;

    if (tid < 64){                       // inline mask decode
        int f = *mflag;
        int i = row0 + tid;
        bool nz;
        if (f == 1)      nz = ((const unsigned char*) maskraw)[i] != 0;
        else if (f == 2) nz = ((const us*)           maskraw)[i] != 0;
        else             nz = ((const unsigned int*) maskraw)[i] != 0;
        sMask[tid] = nz ? 1.0f : 0.0f;
    }

    // ========== GEMM1: pos_feat @ fw1 ==========
    // chunk kc = fw1 rows kc*128..+128 = heads 2kc,2kc+1 ([cos32|sin32] each)
    floatx4 h1a[4] = {};
    {
        const int r  = tid >> 3;
        const int e0 = (tid & 7) * 8;
        const int sb = r * 136 + ((e0 >> 5) << 6) + (e0 & 31);
        float xv[8];
        load8(xv, theta, (size_t)(row0 + r) * NS_ + e0, df);
        for (int kc = 0; kc < 8; ++kc){
            short8 c8v, s8v;
            #pragma unroll
            for (int j = 0; j < 8; ++j){
                float s, c;
                __sincosf(xv[j], &s, &c);
                c8v[j] = (short)f2bf(c);
                s8v[j] = (short)f2bf(s);
            }
            us* dst = &sPF[kc & 1][sb];
            *(short8*)dst        = c8v;
            *(short8*)(dst + 32) = s8v;
            if (kc < 7) load8(xv, theta, (size_t)(row0 + r) * NS_ + (kc + 1) * 64 + e0, df);
            bar();
            const us* fp = fw1t + kc * 16384 + wid * 2048 + lane * 8;
            #pragma unroll
            for (int ks = 0; ks < 4; ++ks){
                short8 b = *(const short8*)(fp + ks * 512);
                #pragma unroll
                for (int mt = 0; mt < 4; ++mt){
                    short8 a = ldfrag(&sPF[kc & 1][(mt*16 + ln) * 136 + ks*32 + q*8]);
                    h1a[mt] = mfma16(a, b, h1a[mt]);
                }
            }
        }
    }
    // epilogue: +fb1, GELU -> sH
    {
        int n = wid * 16 + ln;
        float bias = bf2f(cb[n]);                           // fb1
        #pragma unroll
        for (int mt = 0; mt < 4; ++mt)
            #pragma unroll
            for (int r2 = 0; r2 < 4; ++r2)
                sH[(mt*16 + q*4 + r2) * 136 + n] = f2bf(gelu_exact(h1a[mt][r2] + bias));
    }
    bar();

    // ===== GEMM2 (h1@fw2) + err + GEMM3 (err@ew1), 128-col chunks =====
    floatx4 h2a[4] = {};
    for (int nc = 0; nc < 8; ++nc){
        const int ncol = nc * 128 + wid * 16 + ln;
        // content for this thread's 16 output cells (direct global, no LDS)
        float cv[16];
        #pragma unroll
        for (int mt = 0; mt < 4; ++mt)
            #pragma unroll
            for (int r2 = 0; r2 < 4; ++r2)
                cv[mt*4 + r2] = ldany(content,
                    (size_t)(row0 + mt*16 + q*4 + r2) * D_ + ncol, df);
        // GEMM2: oa = h1 @ fw2[:, chunk nc]
        floatx4 oa[4] = {};
        {
            const us* fp = fw2t + nc * 16384 + wid * 2048 + lane * 8;
            #pragma unroll
            for (int ks = 0; ks < 4; ++ks){
                short8 b = *(const short8*)(fp + ks * 512);
                #pragma unroll
                for (int mt = 0; mt < 4; ++mt){
                    short8 a = ldfrag(&sH[(mt*16 + ln) * 136 + ks*32 + q*8]);
                    oa[mt] = mfma16(a, b, oa[mt]);
                }
            }
        }
        // err epilogue: err_raw -> global, masked err (bf16) -> sPF[nc&1]
        {
            float bias = bf2f(cb[128 + ncol]);              // fb2
            #pragma unroll
            for (int mt = 0; mt < 4; ++mt)
                #pragma unroll
                for (int r2 = 0; r2 < 4; ++r2){
                    int m = mt*16 + q*4 + r2;
                    float obs  = oa[mt][r2] + bias;
                    float eraw = cv[mt*4 + r2] - obs;
                    err_out[(size_t)(row0 + m) * D_ + ncol] = eraw;
                    sPF[nc & 1][m * 136 + wid*16 + ln] = f2bf(eraw * sMask[m]);
                }
        }
        bar();
        // GEMM3: h2a += err_chunk @ ew1[chunk nc rows]
        {
            const us* fp = ew1t + nc * 16384 + wid * 2048 + lane * 8;
            #pragma unroll
            for (int ks = 0; ks < 4; ++ks){
                short8 b = *(const short8*)(fp + ks * 512);
                #pragma unroll
                for (int mt = 0; mt < 4; ++mt){
                    short8 a = ldfrag(&sPF[nc & 1][(mt*16 + ln) * 136 + ks*32 + q*8]);
                    h2a[mt] = mfma16(a, b, h2a[mt]);
                }
            }
        }
    }
    // epilogue: +eb1, GELU -> sH
    {
        int n = wid * 16 + ln;
        float bias = bf2f(cb[1152 + n]);                    // eb1
        #pragma unroll
        for (int mt = 0; mt < 4; ++mt)
            #pragma unroll
            for (int r2 = 0; r2 < 4; ++r2)
                sH[(mt*16 + q*4 + r2) * 136 + n] = f2bf(gelu_exact(h2a[mt][r2] + bias));
    }
    bar();

    // ========== GEMM4: h2 @ ew2 -> delta (no barriers) ==========
    for (int c4 = 0; c4 < 4; ++c4){
        floatx4 da[4] = {};
        const us* fp = ew2t + c4 * 16384 + wid * 2048 + lane * 8;
        #pragma unroll
        for (int ks = 0; ks < 4; ++ks){
            short8 b = *(const short8*)(fp + ks * 512);
            #pragma unroll
            for (int mt = 0; mt < 4; ++mt){
                short8 a = ldfrag(&sH[(mt*16 + ln) * 136 + ks*32 + q*8]);
                da[mt] = mfma16(a, b, da[mt]);
            }
        }
        int ncol = c4 * 128 + wid * 16 + ln;
        float bias = bf2f(cb[1280 + ncol]);                 // eb2
        #pragma unroll
        for (int mt = 0; mt < 4; ++mt)
            #pragma unroll
            for (int r2 = 0; r2 < 4; ++r2){
                int m = mt*16 + q*4 + r2;
                delta_out[(size_t)(row0 + m) * NS_ + ncol] = da[mt][r2] + bias;
            }
    }
}

// -------- phase 1: per-chunk warm-start states (separate dispatch, so the
// in-place scan has no cross-block read/write race on delta) --------
__global__ __launch_bounds__(512) void warmup_k(
    const float* __restrict__ delta, const us* __restrict__ cb,
    float* __restrict__ warm)
{
    int c  = threadIdx.x;
    int bi = blockIdx.x;            // b*NCH + ch
    int ch = bi & (NCH - 1);
    float g = 1.0f / (1.0f + expf(-bf2f(cb[1792 + c])));
    float w = 0.0f;
    if (ch > 0){
        int b  = bi >> 6;
        int t0 = ch * LCH;
        const float* dp = delta + ((size_t)b * T_ + t0 - WARM) * NS_ + c;
        #pragma unroll 8
        for (int t = 0; t < WARM; ++t){ w = g * w + *dp; dp += NS_; }
    }
    warm[bi * NS_ + c] = w;
}

// -------- phase 2: in-place scan: out0 holds delta, becomes theta_hat --------
__global__ __launch_bounds__(512) void scan_k(
    const void* __restrict__ theta, const us* __restrict__ cb,
    const int* __restrict__ dflag, const float* __restrict__ warm,
    float* __restrict__ out0, float* __restrict__ gate_out)
{
    int c  = threadIdx.x;           // chain 0..511
    int bi = blockIdx.x;
    int b  = bi >> 6;
    int ch = bi & (NCH - 1);
    float g = 1.0f / (1.0f + expf(-bf2f(cb[1792 + c])));
    if (bi == 0) gate_out[c] = g;

    float d = warm[bi * NS_ + c];
    size_t base = ((size_t)b * T_ + ch * LCH) * NS_ + c;
    float* op = out0 + base;
    if (*dflag){
        const us* tp = (const us*)theta + base;
        #pragma unroll 4
        for (int t = 0; t < LCH; ++t){
            d = g * d + *op;                  // read delta (fp32)
            *op = bf2f(*tp) + d;              // overwrite with theta_hat
            tp += NS_; op += NS_;
        }
    } else {
        const float* tp = (const float*)theta + base;
        #pragma unroll 4
        for (int t = 0; t < LCH; ++t){
            d = g * d + *op;
            *op = *tp + d;
            tp += NS_; op += NS_;
        }
    }
}

extern "C" void kernel_launch(void* const* d_in, const int* in_sizes, int n_in,
                              void* d_out, int out_size, void* d_ws, size_t ws_size,
                              hipStream_t stream)
{
    const void* theta   = d_in[0];
    const void* content = d_in[1];
    const void* maskraw = d_in[2];
    const void* fw1 = d_in[3];  const void* fb1 = d_in[4];
    const void* fw2 = d_in[5];  const void* fb2 = d_in[6];
    const void* ew1 = d_in[7];  const void* eb1 = d_in[8];
    const void* ew2 = d_in[9];  const void* eb2 = d_in[10];
    const void* lg  = d_in[11];

    char* ws = (char*)d_ws;
    int*   flag  = (int*)ws;                // @0
    int*   dflag = (int*)(ws + 4);          // @4
    us*    cb    = (us*)(ws + 256);         // 4608 B -> ends 4864
    us*    fw1t  = (us*)(ws + 4864);        // 262144 B
    us*    fw2t  = (us*)(ws + 267008);      // 262144 B
    us*    ew1t  = (us*)(ws + 529152);      // 262144 B
    us*    ew2t  = (us*)(ws + 791296);      // 131072 B -> ends 922368
    // warmb aliases the weight region: weights are dead once fused_mlp is done,
    // warmup_k runs strictly after. cb (used by scan) is outside the overlap.
    float* warmb = (float*)(ws + 4864);     // 8*64*512*4 = 1,048,576 B

    float* out0 = (float*)d_out;           // theta_hat (16,777,216 fp32) [delta staged here]
    float* out1 = out0 + 16777216;         // err_raw   (33,554,432 fp32)
    float* out2 = out1 + 33554432;         // gate      (512 fp32)

    dtype_classify<<<1, 256, 0, stream>>>((const us*)theta, dflag);
    mask_classify<<<1, 256, 0, stream>>>((const unsigned char*)maskraw, flag);
    prep_weights<<<512, 256, 0, stream>>>(fw1, fw2, ew1, ew2, fb1, fb2, eb1, eb2,
                                          lg, dflag, fw1t, fw2t, ew1t, ew2t, cb);
    fused_mlp<<<RTOK / 64, 512, 0, stream>>>(theta, content, dflag, maskraw, flag,
                                             cb, fw1t, fw2t, ew1t, ew2t, out1, out0);
    warmup_k<<<B_ * NCH, 512, 0, stream>>>(out0, cb, warmb);
    scan_k<<<B_ * NCH, 512, 0, stream>>>(theta, cb, dflag, warmb, out0, out2);
}